// Round 8
// baseline (701.143 us; speedup 1.0000x reference)
//
#include <hip/hip_runtime.h>

// GAT layer, N=8192, F_IN=512, F_OUT=256. ALL tensors f32; adj int32.
// out = softmax_row(mask(leaky(s1_i+s2_j))) @ h, h = X@W, s{1,2} = h_f32@a{1,2}.
//
// R17 -> R18:
//  * R17 counters: 2 blocks/CU (VGPR 88, LDS 51KB) doubled per-CU B volume
//    (R14 mechanism) + serial adj pre-loop -> 200us attn. Reverted both.
//  * Model: loop is STALL-bound at 2 waves/SIMD (all pipes <20%). R18 raises
//    occupancy without duplicating traffic: ONE 1024-thr block/CU (16 waves),
//    same 32 rows, waves K-SPLIT: waves 0-7 do K-tiles 0..31, waves 8-15 do
//    32..63. Per-CU B/adj/LDS/MFMA/exp volumes IDENTICAL to R13; steps 64->32
//    (half the barriers); 4 waves/SIMD latency hiding.
//  * P[kh][dbuf] (34.8 KB); epilogue combines K-half partials through LDS
//    (reuses P memory) and denominators via dsh[2][32].
//  * launch_bounds(1024) caps VGPR at 128 (measured 88 for this state).

typedef __attribute__((ext_vector_type(8))) short bf16x8;
typedef __attribute__((ext_vector_type(4))) float fx4;
typedef __attribute__((ext_vector_type(4))) int ix4;
typedef __attribute__((ext_vector_type(2))) unsigned int ux2;

#define NN 8192
#define FIN 512
#define FOUT 256
#define PS 136     // LDS P row stride (shorts); 272B stride -> conflict-free b128
#define AROWS 32   // attn rows per block
#define ESTR 260   // epilogue LDS f32 stride (bank-rotating)

__device__ __forceinline__ unsigned short f2bf(float f) {
    unsigned int x = __float_as_uint(f);
    x += 0x7fffu + ((x >> 16) & 1u);
    return (unsigned short)(x >> 16);
}
__device__ __forceinline__ bf16x8 pack8(fx4 a, fx4 b) {
    bf16x8 r;
    r[0] = (short)f2bf(a[0]); r[1] = (short)f2bf(a[1]);
    r[2] = (short)f2bf(a[2]); r[3] = (short)f2bf(a[3]);
    r[4] = (short)f2bf(b[0]); r[5] = (short)f2bf(b[1]);
    r[6] = (short)f2bf(b[2]); r[7] = (short)f2bf(b[3]);
    return r;
}

// ---------- kernel 0: WTt[((k>>5)*256+c)*32 + (k&31)] = bf16(W[k][c]) ----------
__global__ void wt_kernel(const float* __restrict__ W,
                          unsigned short* __restrict__ WTt) {
    const int c = threadIdx.x;
    const int k = blockIdx.x;
    WTt[((size_t)(k >> 5) * 256 + c) * 32 + (k & 31)] = f2bf(W[k * FOUT + c]);
}

// ---------- kernel 1: h-tile (MFMA) + fused s1/s2 ----------
__global__ __launch_bounds__(256) void prep_kernel(
    const float* __restrict__ X,              // 8192x512 f32
    const unsigned short* __restrict__ WTt,   // tiled 256x512 bf16
    const float* __restrict__ A,              // 512 f32 (a1|a2)
    unsigned short* __restrict__ hTt,         // tiled 256x8192 bf16
    float* __restrict__ s1, float* __restrict__ s2)
{
    __shared__ float s1sh[4][16], s2sh[4][16];
    const int tid = threadIdx.x;

    const int w = tid >> 6, l = tid & 63, q = l >> 4, lr = l & 15;
    const int r0 = blockIdx.x * 16;
    const int cbase = w * 64;
    fx4 acc[4] = {};

    for (int kb = 0; kb < FIN; kb += 32) {
        const float* xp = X + (size_t)(r0 + lr) * FIN + kb + q * 8;
        bf16x8 a0 = pack8(*(const fx4*)xp, *(const fx4*)(xp + 4));
#pragma unroll
        for (int tc = 0; tc < 4; ++tc) {
            bf16x8 b = *(const bf16x8*)(WTt + ((size_t)(kb >> 5) * 256 + cbase + tc * 16 + lr) * 32 + q * 8);
            acc[tc] = __builtin_amdgcn_mfma_f32_16x16x32_bf16(a0, b, acc[tc], 0, 0, 0);
        }
    }

    // tiled hTt write
    const int jb = r0 >> 5, jo = (r0 & 31) + q * 4;
#pragma unroll
    for (int tc = 0; tc < 4; ++tc) {
        const int c = cbase + tc * 16 + lr;
        ux2 hp;
        hp.x = (unsigned)f2bf(acc[tc][0]) | ((unsigned)f2bf(acc[tc][1]) << 16);
        hp.y = (unsigned)f2bf(acc[tc][2]) | ((unsigned)f2bf(acc[tc][3]) << 16);
        *(ux2*)(hTt + ((size_t)jb * 256 + c) * 32 + jo) = hp;
    }

    // fused s1/s2 from f32 accumulators
    float p1[4] = {}, p2[4] = {};
#pragma unroll
    for (int tc = 0; tc < 4; ++tc) {
        const int c = cbase + tc * 16 + lr;
        const float a1v = A[c], a2v = A[FOUT + c];
#pragma unroll
        for (int r = 0; r < 4; ++r) {
            p1[r] += acc[tc][r] * a1v;
            p2[r] += acc[tc][r] * a2v;
        }
    }
#pragma unroll
    for (int r = 0; r < 4; ++r) {
#pragma unroll
        for (int off = 1; off < 16; off <<= 1) {
            p1[r] += __shfl_xor(p1[r], off);
            p2[r] += __shfl_xor(p2[r], off);
        }
        if (lr == 0) { s1sh[w][q * 4 + r] = p1[r]; s2sh[w][q * 4 + r] = p2[r]; }
    }
    __syncthreads();
    if (tid < 16) {
        s1[r0 + tid] = s1sh[0][tid] + s1sh[1][tid] + s1sh[2][tid] + s1sh[3][tid];
        s2[r0 + tid] = s2sh[0][tid] + s2sh[1][tid] + s2sh[2][tid] + s2sh[3][tid];
    }
}

// ---------- kernel 2: fused masked-softmax @ h, f32 out ----------
// Grid 256 x 1024 thr (16 waves, ONE block/CU). kh = tid>>9 K-half split:
// waves 0-7 / P-gen threads 0-511 handle K-tiles 0..31; waves 8-15 / threads
// 512-1023 handle 32..63. Per-CU traffic identical to R13; 32 steps; 4
// waves/SIMD. P[kh][dbuf] in LDS; adj nt-streamed 2 steps ahead; B dbuf 1
// step ahead; lgkm-only barrier per step; K-half partials combined in LDS.
__global__ __launch_bounds__(1024) void attn_kernel(
    const int* __restrict__ adj,             // 8192 x 8192 i32
    const unsigned short* __restrict__ hTt,  // tiled 256 x 8192 bf16
    const float* __restrict__ s1,
    const float* __restrict__ s2,
    float* __restrict__ out)                 // 8192 x 256 f32
{
    __shared__ unsigned short P[2][2][AROWS * PS];   // [kh][dbuf], 34.8 KB
    __shared__ float dsh[2][AROWS];

    const int tid = threadIdx.x;
    const int r0 = blockIdx.x * AROWS;
    const int kh = tid >> 9;                   // K-half (both roles)
    const int khB = kh << 5;                   // first K-tile of this half

    // P-generation role: thread -> (row, 8-col group) within its K-half
    const int prow = (tid >> 4) & 31;          // 0..31
    const int pq = tid & 15;                   // cols pq*8..+7
    const float s1v = s1[r0 + prow];
    const int* arow = adj + (size_t)(r0 + prow) * NN + pq * 8;
    float denp = 0.f;

    // MFMA role: wave w: kh=w>>3, cols (w&7)*32..+31
    const int w = tid >> 6, l = tid & 63, q = l >> 4, lr = l & 15;
    const int cbase = (w & 7) * 32;
    fx4 acc[2][2] = {};

    struct LSet { ix4 v0, v1; fx4 s2a, s2b; };
    LSet LA, LB;
    bf16x8 B0[4][2], B1[4][2];

    auto loadS = [&](int s, LSet& L) {         // inputs for K-tile khB+s
        const int kt = khB + s;
        const int* ap = arow + kt * 128;
        L.v0 = __builtin_nontemporal_load((const ix4*)ap);
        L.v1 = __builtin_nontemporal_load((const ix4*)(ap + 4));
        L.s2a = *(const fx4*)(s2 + kt * 128 + pq * 8);
        L.s2b = *(const fx4*)(s2 + kt * 128 + pq * 8 + 4);
    };
    auto calcP = [&](int b, const LSet& L) {   // writes P[kh][b]
        bf16x8 pv;
#pragma unroll
        for (int j = 0; j < 8; ++j) {
            const int aj = (j < 4) ? L.v0[j] : L.v1[j - 4];
            const float s2j = (j < 4) ? L.s2a[j] : L.s2b[j - 4];
            float t = s1v + s2j;
            float e = fmaxf(t, 0.2f * t);      // leaky_relu, alpha=0.2
            e = fminf(e, 30.f);                // overflow guard (inactive)
            const float p = (aj != 0) ? __expf(e) : 0.f;
            denp += p;
            pv[j] = (short)f2bf(p);
        }
        *(bf16x8*)(&P[kh][b][prow * PS + pq * 8]) = pv;   // 16B store
    };
    auto loadB = [&](int s, bf16x8 (&B)[4][2]) {
        const int kt = khB + s;
#pragma unroll
        for (int ks = 0; ks < 4; ++ks)
#pragma unroll
            for (int tc = 0; tc < 2; ++tc)
                B[ks][tc] = *(const bf16x8*)(hTt + ((size_t)(kt * 4 + ks) * 256 + cbase + tc * 16 + lr) * 32 + q * 8);
    };

    // LDS-only barrier: ds ops drained (lgkmcnt), global loads stay in flight.
    auto ldsBarrier = [&]() {
        asm volatile("s_waitcnt lgkmcnt(0)" ::: "memory");
        __builtin_amdgcn_s_barrier();
    };

    const int STEPS = 32;         // K-tiles per half

    loadS(0, LA);
    calcP(0, LA);                 // P[kh][0] for step 0
    loadS(1, LA);
    loadB(0, B0);
    ldsBarrier();

    auto body = [&](int s, bf16x8 (&Bc)[4][2], bf16x8 (&Bn)[4][2],
                    LSet& Lc, LSet& Ln) {
        if (s + 1 < STEPS) loadB(s + 1, Bn);       // in flight across barrier
        if (s + 2 < STEPS) loadS(s + 2, Ln);       // 2-deep adj/s2 stream
        const unsigned short* Pb = P[kh][s & 1];
        bf16x8 af0[4], af1[4];
#pragma unroll
        for (int ks = 0; ks < 4; ++ks) {
            af0[ks] = *(const bf16x8*)(Pb + lr * PS + ks * 32 + q * 8);
            af1[ks] = *(const bf16x8*)(Pb + (16 + lr) * PS + ks * 32 + q * 8);
        }
        __builtin_amdgcn_s_setprio(1);
#pragma unroll
        for (int ks = 0; ks < 4; ++ks)
#pragma unroll
            for (int tc = 0; tc < 2; ++tc) {
                acc[0][tc] = __builtin_amdgcn_mfma_f32_16x16x32_bf16(af0[ks], Bc[ks][tc], acc[0][tc], 0, 0, 0);
                acc[1][tc] = __builtin_amdgcn_mfma_f32_16x16x32_bf16(af1[ks], Bc[ks][tc], acc[1][tc], 0, 0, 0);
            }
        __builtin_amdgcn_s_setprio(0);
        if (s + 1 < STEPS) calcP((s + 1) & 1, Lc);
        ldsBarrier();
    };

    for (int s = 0; s < STEPS; s += 2) {
        body(s, B0, B1, LA, LB);
        body(s + 1, B1, B0, LB, LA);
    }

    // den: per-half reduce over the 16 lanes sharing a row
    float v = denp;
    v += __shfl_xor(v, 1);
    v += __shfl_xor(v, 2);
    v += __shfl_xor(v, 4);
    v += __shfl_xor(v, 8);
    if (pq == 0) dsh[kh][prow] = v;
    __syncthreads();

    // K-half combine: kh=1 waves stash partial acc in LDS (reuse P memory)
    float* epi = (float*)&P[0][0][0];          // 33.3 KB needed <= 34.8 KB
    if (kh == 1) {
#pragma unroll
        for (int mg = 0; mg < 2; ++mg)
#pragma unroll
            for (int r = 0; r < 4; ++r) {
                const int row = mg * 16 + q * 4 + r;
#pragma unroll
                for (int tc = 0; tc < 2; ++tc)
                    epi[row * ESTR + cbase + tc * 16 + lr] = acc[mg][tc][r];
            }
    }
    __syncthreads();

    if (kh == 0) {
#pragma unroll
        for (int mg = 0; mg < 2; ++mg)
#pragma unroll
            for (int r = 0; r < 4; ++r) {
                const int row = mg * 16 + q * 4 + r;
                const float dinv = 1.0f / fmaxf(dsh[0][row] + dsh[1][row], 1e-30f);
#pragma unroll
                for (int tc = 0; tc < 2; ++tc) {
                    const int col = cbase + tc * 16 + lr;
                    out[(size_t)(r0 + row) * FOUT + col] =
                        (acc[mg][tc][r] + epi[row * ESTR + col]) * dinv;
                }
            }
    }
}

extern "C" void kernel_launch(void* const* d_in, const int* in_sizes, int n_in,
                              void* d_out, int out_size, void* d_ws, size_t ws_size,
                              hipStream_t stream) {
    const float *X = nullptr, *W = nullptr, *A = nullptr;
    const int* adj = nullptr;
    for (int i = 0; i < n_in; ++i) {
        switch (in_sizes[i]) {
            case NN * FIN:   X = (const float*)d_in[i]; break;
            case FIN * FOUT: W = (const float*)d_in[i]; break;
            case 2 * FOUT:   A = (const float*)d_in[i]; break;
            case NN * NN:    adj = (const int*)d_in[i]; break;
        }
    }
    if (!X) X = (const float*)d_in[0];
    if (!W) W = (const float*)d_in[1];
    if (!A) A = (const float*)d_in[2];
    if (!adj) adj = (const int*)d_in[3];
    float* out = (float*)d_out;

    // ws layout (subset of the 1 GiB ws):
    char* ws = (char*)d_ws;
    float* s1 = (float*)ws;                                 // 32 KB
    float* s2 = (float*)(ws + 32768);                       // 32 KB
    unsigned short* WTt = (unsigned short*)(ws + 98304);    // 256 KB
    unsigned short* hTt = (unsigned short*)(ws + 360448);   // 4 MB

    wt_kernel<<<512, 256, 0, stream>>>(W, WTt);
    prep_kernel<<<512, 256, 0, stream>>>(X, WTt, A, hTt, s1, s2);
    attn_kernel<<<NN / AROWS, 1024, 0, stream>>>(adj, hTt, s1, s2, out);
}

// Round 9
// 475.090 us; speedup vs baseline: 1.4758x; 1.4758x over previous
//
#include <hip/hip_runtime.h>

// GAT layer, N=8192, F_IN=512, F_OUT=256. ALL tensors f32; adj int32.
// out = softmax_row(mask(leaky(s1_i+s2_j))) @ h, h = X@W, s{1,2} = h_f32@a{1,2}.
//
// R18 -> R19:
//  * R18: launch_bounds(1024) clamped VGPR to 64 -> 1.2 GB scratch spills
//    (WRITE_SIZE 620 MB). Reverted. Constraint learned: need 130-190 VGPR.
//  * Series synthesis: scheduling fixes all null; attn time tracks per-CU
//    B-fragment volume (64 KB/iter -> 109us; 128 KB/iter -> 166-200us).
//  * R19 halves per-CU B volume at full occupancy: 64 rows x 128 cols per
//    block (grid 256, 1 block/CU). R11 tried this and regressed, but with a
//    fat 16-wide calcP (suspected spill). Here: R13-verbatim narrow structure,
//    calcP 8-wide called twice (kq=0/1), lean LSets (~190 VGPR est).
//  * ch = blockIdx&1 == XCD parity: each XCD's L2 serves ONE 2 MB hTt half.
//  * Cost: adj read twice chip-wide (L3-damped), exp VALU x2 (overlapped).

typedef __attribute__((ext_vector_type(8))) short bf16x8;
typedef __attribute__((ext_vector_type(4))) float fx4;
typedef __attribute__((ext_vector_type(4))) int ix4;
typedef __attribute__((ext_vector_type(2))) unsigned int ux2;

#define NN 8192
#define FIN 512
#define FOUT 256
#define PS 136     // LDS P row stride (shorts); 272B stride -> conflict-free b128
#define AROWS 64   // attn rows per block (x 128-col half)

__device__ __forceinline__ unsigned short f2bf(float f) {
    unsigned int x = __float_as_uint(f);
    x += 0x7fffu + ((x >> 16) & 1u);
    return (unsigned short)(x >> 16);
}
__device__ __forceinline__ bf16x8 pack8(fx4 a, fx4 b) {
    bf16x8 r;
    r[0] = (short)f2bf(a[0]); r[1] = (short)f2bf(a[1]);
    r[2] = (short)f2bf(a[2]); r[3] = (short)f2bf(a[3]);
    r[4] = (short)f2bf(b[0]); r[5] = (short)f2bf(b[1]);
    r[6] = (short)f2bf(b[2]); r[7] = (short)f2bf(b[3]);
    return r;
}

// ---------- kernel 0: WTt[((k>>5)*256+c)*32 + (k&31)] = bf16(W[k][c]) ----------
__global__ void wt_kernel(const float* __restrict__ W,
                          unsigned short* __restrict__ WTt) {
    const int c = threadIdx.x;
    const int k = blockIdx.x;
    WTt[((size_t)(k >> 5) * 256 + c) * 32 + (k & 31)] = f2bf(W[k * FOUT + c]);
}

// ---------- kernel 1: h-tile (MFMA) + fused s1/s2 ----------
__global__ __launch_bounds__(256) void prep_kernel(
    const float* __restrict__ X,              // 8192x512 f32
    const unsigned short* __restrict__ WTt,   // tiled 256x512 bf16
    const float* __restrict__ A,              // 512 f32 (a1|a2)
    unsigned short* __restrict__ hTt,         // tiled 256x8192 bf16
    float* __restrict__ s1, float* __restrict__ s2)
{
    __shared__ float s1sh[4][16], s2sh[4][16];
    const int tid = threadIdx.x;

    const int w = tid >> 6, l = tid & 63, q = l >> 4, lr = l & 15;
    const int r0 = blockIdx.x * 16;
    const int cbase = w * 64;
    fx4 acc[4] = {};

    for (int kb = 0; kb < FIN; kb += 32) {
        const float* xp = X + (size_t)(r0 + lr) * FIN + kb + q * 8;
        bf16x8 a0 = pack8(*(const fx4*)xp, *(const fx4*)(xp + 4));
#pragma unroll
        for (int tc = 0; tc < 4; ++tc) {
            bf16x8 b = *(const bf16x8*)(WTt + ((size_t)(kb >> 5) * 256 + cbase + tc * 16 + lr) * 32 + q * 8);
            acc[tc] = __builtin_amdgcn_mfma_f32_16x16x32_bf16(a0, b, acc[tc], 0, 0, 0);
        }
    }

    // tiled hTt write
    const int jb = r0 >> 5, jo = (r0 & 31) + q * 4;
#pragma unroll
    for (int tc = 0; tc < 4; ++tc) {
        const int c = cbase + tc * 16 + lr;
        ux2 hp;
        hp.x = (unsigned)f2bf(acc[tc][0]) | ((unsigned)f2bf(acc[tc][1]) << 16);
        hp.y = (unsigned)f2bf(acc[tc][2]) | ((unsigned)f2bf(acc[tc][3]) << 16);
        *(ux2*)(hTt + ((size_t)jb * 256 + c) * 32 + jo) = hp;
    }

    // fused s1/s2 from f32 accumulators
    float p1[4] = {}, p2[4] = {};
#pragma unroll
    for (int tc = 0; tc < 4; ++tc) {
        const int c = cbase + tc * 16 + lr;
        const float a1v = A[c], a2v = A[FOUT + c];
#pragma unroll
        for (int r = 0; r < 4; ++r) {
            p1[r] += acc[tc][r] * a1v;
            p2[r] += acc[tc][r] * a2v;
        }
    }
#pragma unroll
    for (int r = 0; r < 4; ++r) {
#pragma unroll
        for (int off = 1; off < 16; off <<= 1) {
            p1[r] += __shfl_xor(p1[r], off);
            p2[r] += __shfl_xor(p2[r], off);
        }
        if (lr == 0) { s1sh[w][q * 4 + r] = p1[r]; s2sh[w][q * 4 + r] = p2[r]; }
    }
    __syncthreads();
    if (tid < 16) {
        s1[r0 + tid] = s1sh[0][tid] + s1sh[1][tid] + s1sh[2][tid] + s1sh[3][tid];
        s2[r0 + tid] = s2sh[0][tid] + s2sh[1][tid] + s2sh[2][tid] + s2sh[3][tid];
    }
}

// ---------- kernel 2: fused masked-softmax @ h, f32 out ----------
// Grid 256 x 512 thr. Block = 64 rows x 128 cols (rg = bid>>1, ch = bid&1).
// 8 waves = 2 row-groups x 4 col-groups; wave = 32 rows x 32 cols (acc[2][2]).
// Per-CU B volume HALVED vs R13 (32 KB/iter). adj nt-streamed (2 iters ahead,
// two 8-k slices/thread); B dbuf 1 iter ahead; P (64x128 bf16) double-buffered;
// lgkm-only barrier; setprio around MFMA. Structure otherwise R13-verbatim.
__global__ __launch_bounds__(512) void attn_kernel(
    const int* __restrict__ adj,             // 8192 x 8192 i32
    const unsigned short* __restrict__ hTt,  // tiled 256 x 8192 bf16
    const float* __restrict__ s1,
    const float* __restrict__ s2,
    float* __restrict__ out)                 // 8192 x 256 f32
{
    __shared__ unsigned short P[2][AROWS * PS];   // 34.8 KB
    __shared__ float dsh[AROWS];

    const int tid = threadIdx.x;
    const int rg = blockIdx.x >> 1;
    const int ch = blockIdx.x & 1;           // column half == XCD parity
    const int r0 = rg * AROWS;
    const int c0 = ch * 128;

    // P-generation role: thread -> (row, two 8-k slices at kq*64 + pq*8)
    const int prow = tid >> 3;                 // 0..63
    const int pq = tid & 7;                    // k-cols pq*8..+7 in each half
    const float s1v = s1[r0 + prow];
    const int* arow = adj + (size_t)(r0 + prow) * NN + pq * 8;
    float denp = 0.f;

    // MFMA role: wave w: rows (w>>2)*32.., cols c0 + (w&3)*32..
    const int w = tid >> 6, l = tid & 63, q = l >> 4, lr = l & 15;
    const int rgw = (w >> 2) * 32;
    const int cbase = c0 + (w & 3) * 32;
    fx4 acc[2][2] = {};

    struct LSet { ix4 v0, v1; fx4 s2a, s2b; };
    LSet SA, SB;                               // kq=0 / kq=1 streams (R13 dance)
    bf16x8 B0[4][2], B1[4][2];

    auto loadS = [&](int kt, int kq, LSet& L) {
        const int* ap = arow + kt * 128 + kq * 64;
        L.v0 = __builtin_nontemporal_load((const ix4*)ap);
        L.v1 = __builtin_nontemporal_load((const ix4*)(ap + 4));
        L.s2a = *(const fx4*)(s2 + kt * 128 + kq * 64 + pq * 8);
        L.s2b = *(const fx4*)(s2 + kt * 128 + kq * 64 + pq * 8 + 4);
    };
    auto calcP = [&](int b, int kq, const LSet& L) {   // writes P[b], k-half kq
        bf16x8 pv;
#pragma unroll
        for (int j = 0; j < 8; ++j) {
            const int aj = (j < 4) ? L.v0[j] : L.v1[j - 4];
            const float s2j = (j < 4) ? L.s2a[j] : L.s2b[j - 4];
            float t = s1v + s2j;
            float e = fmaxf(t, 0.2f * t);      // leaky_relu, alpha=0.2
            e = fminf(e, 30.f);                // overflow guard (inactive)
            const float p = (aj != 0) ? __expf(e) : 0.f;
            denp += p;
            pv[j] = (short)f2bf(p);
        }
        *(bf16x8*)(&P[b][prow * PS + kq * 64 + pq * 8]) = pv;   // 16B store
    };
    auto loadB = [&](int it, bf16x8 (&B)[4][2]) {
#pragma unroll
        for (int ks = 0; ks < 4; ++ks)
#pragma unroll
            for (int tc = 0; tc < 2; ++tc)
                B[ks][tc] = *(const bf16x8*)(hTt + ((size_t)(it * 4 + ks) * 256 + cbase + tc * 16 + lr) * 32 + q * 8);
    };

    // LDS-only barrier: ds ops drained (lgkmcnt), global loads stay in flight.
    auto ldsBarrier = [&]() {
        asm volatile("s_waitcnt lgkmcnt(0)" ::: "memory");
        __builtin_amdgcn_s_barrier();
    };

    const int ITERS = NN / 128;   // 64
    loadS(0, 0, SA); loadS(0, 1, SB);
    calcP(0, 0, SA); calcP(0, 1, SB);          // P[0]
    loadS(1, 0, SA); loadS(1, 1, SB);          // overwrite after consumption
    loadB(0, B0);
    ldsBarrier();

    // body(it): loadB(it+1); af from P[it&1]; MFMA; calcP(it+1) from S* loaded
    // at body(it-1); reload S* for it+2; barrier. (R13-verbatim schedule.)
    auto body = [&](int it, bf16x8 (&Bc)[4][2], bf16x8 (&Bn)[4][2]) {
        if (it + 1 < ITERS) loadB(it + 1, Bn);     // in flight across barrier
        const unsigned short* Pb = P[it & 1];
        bf16x8 af0[4], af1[4];
#pragma unroll
        for (int ks = 0; ks < 4; ++ks) {
            af0[ks] = *(const bf16x8*)(Pb + (rgw + lr) * PS + ks * 32 + q * 8);
            af1[ks] = *(const bf16x8*)(Pb + (rgw + 16 + lr) * PS + ks * 32 + q * 8);
        }
        __builtin_amdgcn_s_setprio(1);
#pragma unroll
        for (int ks = 0; ks < 4; ++ks)
#pragma unroll
            for (int tc = 0; tc < 2; ++tc) {
                acc[0][tc] = __builtin_amdgcn_mfma_f32_16x16x32_bf16(af0[ks], Bc[ks][tc], acc[0][tc], 0, 0, 0);
                acc[1][tc] = __builtin_amdgcn_mfma_f32_16x16x32_bf16(af1[ks], Bc[ks][tc], acc[1][tc], 0, 0, 0);
            }
        __builtin_amdgcn_s_setprio(0);
        if (it + 1 < ITERS) {
            calcP((it + 1) & 1, 0, SA);            // consume (loaded last body)
            calcP((it + 1) & 1, 1, SB);
        }
        if (it + 2 < ITERS) {
            loadS(it + 2, 0, SA);                  // refill for next body
            loadS(it + 2, 1, SB);
        }
        ldsBarrier();
    };

    for (int it = 0; it < ITERS; it += 2) {
        body(it, B0, B1);
        body(it + 1, B1, B0);
    }

    // den: reduce over the 8 lanes sharing a row
    float v = denp;
    v += __shfl_xor(v, 1);
    v += __shfl_xor(v, 2);
    v += __shfl_xor(v, 4);
    if (pq == 0) dsh[prow] = v;
    __syncthreads();

#pragma unroll
    for (int mg = 0; mg < 2; ++mg) {
#pragma unroll
        for (int r = 0; r < 4; ++r) {
            const int row = rgw + mg * 16 + q * 4 + r;
            const float dinv = 1.0f / fmaxf(dsh[row], 1e-30f);
#pragma unroll
            for (int tc = 0; tc < 2; ++tc) {
                out[(size_t)(r0 + row) * FOUT + cbase + tc * 16 + lr] = acc[mg][tc][r] * dinv;
            }
        }
    }
}

extern "C" void kernel_launch(void* const* d_in, const int* in_sizes, int n_in,
                              void* d_out, int out_size, void* d_ws, size_t ws_size,
                              hipStream_t stream) {
    const float *X = nullptr, *W = nullptr, *A = nullptr;
    const int* adj = nullptr;
    for (int i = 0; i < n_in; ++i) {
        switch (in_sizes[i]) {
            case NN * FIN:   X = (const float*)d_in[i]; break;
            case FIN * FOUT: W = (const float*)d_in[i]; break;
            case 2 * FOUT:   A = (const float*)d_in[i]; break;
            case NN * NN:    adj = (const int*)d_in[i]; break;
        }
    }
    if (!X) X = (const float*)d_in[0];
    if (!W) W = (const float*)d_in[1];
    if (!A) A = (const float*)d_in[2];
    if (!adj) adj = (const int*)d_in[3];
    float* out = (float*)d_out;

    // ws layout (subset of the 1 GiB ws):
    char* ws = (char*)d_ws;
    float* s1 = (float*)ws;                                 // 32 KB
    float* s2 = (float*)(ws + 32768);                       // 32 KB
    unsigned short* WTt = (unsigned short*)(ws + 98304);    // 256 KB
    unsigned short* hTt = (unsigned short*)(ws + 360448);   // 4 MB

    wt_kernel<<<512, 256, 0, stream>>>(W, WTt);
    prep_kernel<<<512, 256, 0, stream>>>(X, WTt, A, hTt, s1, s2);
    attn_kernel<<<(NN / AROWS) * 2, 512, 0, stream>>>(adj, hTt, s1, s2, out);
}